// Round 1
// baseline (321.066 us; speedup 1.0000x reference)
//
#include <hip/hip_runtime.h>

// BatchSampler: replicate JAX reference exactly enough that the Gumbel-max
// argmax token per row matches. One block per row; 8 streaming passes.
//
// Pass 1 : m = max(x), top-k L0 count hist
// Pass 2-3: top-k radix descent (11/11/10 bit) -> tau_k, rem_k
// Pass 4 : Z1 + top-p L0 sum hist (u64 fixed-point 2^-44, exact/deterministic)
// Pass 5-6: top-p descent -> boundary class t2, rem_p, Z2
// Pass 7 : min-p predicate + Z3 + tie-index list -> I2 (stable-tie cutoff)
// Pass 8 : argmax over kept of logf(e/Z3) + gumbel(threefry partitionable)

#define TPB 1024
#define VOC 128256
#define V4 (VOC / 4)
#define NCH ((V4 + TPB - 1) / TPB)
#define NB 2048
#define NB2 1024
#define TIE_CAP 1024
#define IMAXI 0x7fffffff
#define FIXS 1.7592186044416e13   // 2^44

__device__ __forceinline__ unsigned fkey(float x) {
  unsigned b = __float_as_uint(x);
  return b ^ ((b & 0x80000000u) ? 0xFFFFFFFFu : 0x80000000u);
}
__device__ __forceinline__ float keyf(unsigned k) {
  unsigned b = (k & 0x80000000u) ? (k ^ 0x80000000u) : ~k;
  return __uint_as_float(b);
}
__device__ __forceinline__ unsigned rotl32(unsigned v, int r) {
  return (v << r) | (v >> (32 - r));
}

// JAX threefry2x32, key=(0,42), partitionable path: counters (0, i), 32-bit
// output = o1 ^ o2. Then jax.random.gumbel's uniform(minval=tiny, maxval=1).
__device__ __forceinline__ float gumbel_at(unsigned i) {
  const unsigned ks1 = 42u;
  const unsigned ks2 = 0x1BD11BDAu ^ 42u;
  unsigned x0 = 0u;            // + ks0 (=0)
  unsigned x1 = i + ks1;
  // group 1: rotations 13,15,26,6
  x0 += x1; x1 = rotl32(x1, 13); x1 ^= x0;
  x0 += x1; x1 = rotl32(x1, 15); x1 ^= x0;
  x0 += x1; x1 = rotl32(x1, 26); x1 ^= x0;
  x0 += x1; x1 = rotl32(x1, 6);  x1 ^= x0;
  x0 += ks1; x1 += ks2 + 1u;
  // group 2: 17,29,16,24
  x0 += x1; x1 = rotl32(x1, 17); x1 ^= x0;
  x0 += x1; x1 = rotl32(x1, 29); x1 ^= x0;
  x0 += x1; x1 = rotl32(x1, 16); x1 ^= x0;
  x0 += x1; x1 = rotl32(x1, 24); x1 ^= x0;
  x0 += ks2; x1 += 0u + 2u;
  // group 3: 13,15,26,6
  x0 += x1; x1 = rotl32(x1, 13); x1 ^= x0;
  x0 += x1; x1 = rotl32(x1, 15); x1 ^= x0;
  x0 += x1; x1 = rotl32(x1, 26); x1 ^= x0;
  x0 += x1; x1 = rotl32(x1, 6);  x1 ^= x0;
  x0 += 0u; x1 += ks1 + 3u;
  // group 4: 17,29,16,24
  x0 += x1; x1 = rotl32(x1, 17); x1 ^= x0;
  x0 += x1; x1 = rotl32(x1, 29); x1 ^= x0;
  x0 += x1; x1 = rotl32(x1, 16); x1 ^= x0;
  x0 += x1; x1 = rotl32(x1, 24); x1 ^= x0;
  x0 += ks1; x1 += ks2 + 4u;
  // group 5: 13,15,26,6
  x0 += x1; x1 = rotl32(x1, 13); x1 ^= x0;
  x0 += x1; x1 = rotl32(x1, 15); x1 ^= x0;
  x0 += x1; x1 = rotl32(x1, 26); x1 ^= x0;
  x0 += x1; x1 = rotl32(x1, 6);  x1 ^= x0;
  x0 += ks2; x1 += 0u + 5u;
  unsigned bits = x0 ^ x1;
  unsigned fb = (bits >> 9) | 0x3f800000u;
  float f = __uint_as_float(fb) - 1.0f;
  float u = (f > 0.0f) ? f : 1.17549435e-38f;   // uniform(tiny, 1.0)
  return -logf(-logf(u));
}

// In-place inclusive suffix scan over H[0..n): H[i] = sum_{j>=i} H_orig[j]
__device__ __forceinline__ void suffix_scan(unsigned long long* H, int n, int tid) {
  for (int d = 1; d < n; d <<= 1) {
    unsigned long long v0 = 0ull, v1 = 0ull;
    int i0 = tid, i1 = tid + TPB;
    bool a0 = (i0 < n), a1 = (i1 < n);
    if (a0) { v0 = H[i0]; if (i0 + d < n) v0 += H[i0 + d]; }
    if (a1) { v1 = H[i1]; if (i1 + d < n) v1 += H[i1 + d]; }
    __syncthreads();
    if (a0) H[i0] = v0;
    if (a1) H[i1] = v1;
    __syncthreads();
  }
}

// Stream the row: provides `idx` (token id) and `x` (logit/temp, exact fp32 div)
#define FOR_ELEMS(...)                                                        \
  for (int c_ = 0; c_ < NCH; ++c_) {                                          \
    const int i4_ = c_ * TPB + tid;                                           \
    if (i4_ < V4) {                                                           \
      const float4 L_ = ((const float4*)rowp)[i4_];                           \
      const float xs_[4] = { L_.x / tclamp, L_.y / tclamp,                    \
                             L_.z / tclamp, L_.w / tclamp };                  \
      const int base_ = i4_ * 4;                                              \
      for (int j_ = 0; j_ < 4; ++j_) {                                        \
        const int idx = base_ + j_; const float x = xs_[j_];                  \
        __VA_ARGS__                                                           \
      }                                                                       \
    }                                                                         \
  }

extern "C" __global__ void __launch_bounds__(TPB)
batch_sampler_kernel(const float* __restrict__ logits,
                     const float* __restrict__ temps,
                     const float* __restrict__ topps,
                     const int*   __restrict__ topks,
                     const float* __restrict__ minps,
                     int* __restrict__ out)
{
  __shared__ unsigned long long H[NB];
  __shared__ unsigned C2[NB2];          // top-p L2 counts; reused as tie list
  __shared__ float  redf[16];
  __shared__ double redd[16];
  __shared__ float  redw[16];
  __shared__ int    redi[16];
  __shared__ int tie_n;
  __shared__ struct {
    float m;
    unsigned long long kk, above;
    int b0, b1, b2, rem_k;
    int I2;
    double Z3;
  } bc;

  const int tid = threadIdx.x;
  const int row = blockIdx.x;
  const float* rowp = logits + (size_t)row * VOC;
  const float tclamp = fmaxf(temps[row], 1e-8f);
  const float topp = topps[row];
  const float minp = minps[row];
  const int k = topks[row];
  const bool ka = (k > 0) && (k < VOC);

  // ---------------- Pass 1: max + top-k L0 count hist ----------------
  for (int i = tid; i < NB; i += TPB) H[i] = 0ull;
  __syncthreads();
  float lmax = -INFINITY;
  FOR_ELEMS(
    lmax = fmaxf(lmax, x);
    if (ka) atomicAdd(&H[fkey(x) >> 21], 1ull);
  )
  for (int o = 32; o > 0; o >>= 1) lmax = fmaxf(lmax, __shfl_down(lmax, o));
  if ((tid & 63) == 0) redf[tid >> 6] = lmax;
  __syncthreads();
  if (tid == 0) {
    float mm = redf[0];
    for (int i = 1; i < 16; ++i) mm = fmaxf(mm, redf[i]);
    bc.m = mm;
  }
  __syncthreads();
  const float m = bc.m;

  // ---------------- Top-k radix descent (counts) ----------------
  unsigned tk_key = 0u; int rem_k = 0;
  if (ka) {
    if (tid == 0) bc.kk = (unsigned long long)k;
    __syncthreads();
    suffix_scan(H, NB, tid);
    {
      unsigned long long kk = bc.kk;
      for (int i = tid; i < NB; i += TPB) {
        unsigned long long hi = H[i], hn = (i + 1 < NB) ? H[i + 1] : 0ull;
        if (hi >= kk && hn < kk) { bc.b0 = i; bc.above = hn; }
      }
    }
    __syncthreads();
    const int b0k = bc.b0;
    if (tid == 0) bc.kk -= bc.above;
    __syncthreads();
    for (int i = tid; i < NB; i += TPB) H[i] = 0ull;
    __syncthreads();
    FOR_ELEMS(
      (void)idx;
      unsigned key = fkey(x);
      if ((int)(key >> 21) == b0k) atomicAdd(&H[(key >> 10) & 0x7FFu], 1ull);
    )
    __syncthreads();
    suffix_scan(H, NB, tid);
    {
      unsigned long long kk = bc.kk;
      for (int i = tid; i < NB; i += TPB) {
        unsigned long long hi = H[i], hn = (i + 1 < NB) ? H[i + 1] : 0ull;
        if (hi >= kk && hn < kk) { bc.b1 = i; bc.above = hn; }
      }
    }
    __syncthreads();
    const int b1k = bc.b1;
    if (tid == 0) bc.kk -= bc.above;
    __syncthreads();
    for (int i = tid; i < NB; i += TPB) H[i] = 0ull;
    __syncthreads();
    const unsigned pathk = ((unsigned)b0k << 11) | (unsigned)b1k;
    FOR_ELEMS(
      (void)idx;
      unsigned key = fkey(x);
      if ((key >> 10) == pathk) atomicAdd(&H[key & 0x3FFu], 1ull);
    )
    __syncthreads();
    suffix_scan(H, NB2, tid);
    {
      unsigned long long kk = bc.kk;
      for (int i = tid; i < NB2; i += TPB) {
        unsigned long long hi = H[i], hn = (i + 1 < NB2) ? H[i + 1] : 0ull;
        if (hi >= kk && hn < kk) { bc.b2 = i; bc.above = hn; }
      }
    }
    __syncthreads();
    if (tid == 0) bc.rem_k = (int)(bc.kk - bc.above);
    __syncthreads();
    tk_key = ((unsigned)b0k << 21) | ((unsigned)b1k << 10) | (unsigned)bc.b2;
    rem_k = bc.rem_k;
  }
  const float e_tk = ka ? expf(keyf(tk_key) - m) : 0.0f;
  const unsigned long long e_tk_fix = (unsigned long long)((double)e_tk * FIXS);

  // ---------------- Pass 4: Z1 + top-p L0 sum hist ----------------
  __syncthreads();
  for (int i = tid; i < NB; i += TPB) H[i] = 0ull;
  __syncthreads();
  FOR_ELEMS(
    (void)idx;
    unsigned key = fkey(x);
    if (!ka || key > tk_key) {
      float e = expf(x - m);
      unsigned long long ef = (unsigned long long)((double)e * FIXS);
      if (ef) atomicAdd(&H[key >> 21], ef);
    }
  )
  __syncthreads();
  if (tid == 0 && ka) H[tk_key >> 21] += (unsigned long long)(unsigned)rem_k * e_tk_fix;
  __syncthreads();
  suffix_scan(H, NB, tid);
  const unsigned long long Z1fix = H[0];
  const unsigned long long Tfix = (unsigned long long)((double)topp * (double)Z1fix);
  const int keepall = (Z1fix <= Tfix);   // only if top_p >= total mass

  unsigned t2_key = 0u; int rem2 = 0, all_mode = 0;
  double Z2d = 0.0; float e_t = 0.0f;

  if (!keepall) {
    // L0 walk: highest bin where inclusive suffix crosses T
    for (int i = tid; i < NB; i += TPB) {
      unsigned long long hi = H[i], hn = (i + 1 < NB) ? H[i + 1] : 0ull;
      if (hi > Tfix && hn <= Tfix) { bc.b0 = i; bc.above = hn; }
    }
    __syncthreads();
    const int b0p = bc.b0;
    const unsigned long long S0 = bc.above;
    // L1
    for (int i = tid; i < NB; i += TPB) H[i] = 0ull;
    __syncthreads();
    FOR_ELEMS(
      (void)idx;
      unsigned key = fkey(x);
      if ((int)(key >> 21) == b0p && (!ka || key > tk_key)) {
        float e = expf(x - m);
        unsigned long long ef = (unsigned long long)((double)e * FIXS);
        if (ef) atomicAdd(&H[(key >> 10) & 0x7FFu], ef);
      }
    )
    __syncthreads();
    if (tid == 0 && ka && (int)(tk_key >> 21) == b0p)
      H[(tk_key >> 10) & 0x7FFu] += (unsigned long long)(unsigned)rem_k * e_tk_fix;
    __syncthreads();
    suffix_scan(H, NB, tid);
    {
      const unsigned long long T1 = Tfix - S0;
      for (int i = tid; i < NB; i += TPB) {
        unsigned long long hi = H[i], hn = (i + 1 < NB) ? H[i + 1] : 0ull;
        if (hi > T1 && hn <= T1) { bc.b1 = i; bc.above = hn; }
      }
    }
    __syncthreads();
    const int b1p = bc.b1;
    const unsigned long long S1 = S0 + bc.above;
    // L2 (exact class level): sums + counts
    for (int i = tid; i < NB; i += TPB) H[i] = 0ull;
    for (int i = tid; i < NB2; i += TPB) C2[i] = 0u;
    __syncthreads();
    const unsigned pathp = ((unsigned)b0p << 11) | (unsigned)b1p;
    FOR_ELEMS(
      (void)idx;
      unsigned key = fkey(x);
      if ((key >> 10) == pathp && (!ka || key > tk_key)) {
        float e = expf(x - m);
        unsigned long long ef = (unsigned long long)((double)e * FIXS);
        atomicAdd(&H[key & 0x3FFu], ef);
        atomicAdd(&C2[key & 0x3FFu], 1u);
      }
    )
    __syncthreads();
    if (tid == 0 && ka && (tk_key >> 10) == pathp) {
      H[tk_key & 0x3FFu] += (unsigned long long)(unsigned)rem_k * e_tk_fix;
      C2[tk_key & 0x3FFu] += (unsigned)rem_k;
    }
    __syncthreads();
    suffix_scan(H, NB2, tid);
    {
      const unsigned long long T2 = Tfix - S1;
      for (int i = tid; i < NB2; i += TPB) {
        unsigned long long hi = H[i], hn = (i + 1 < NB2) ? H[i + 1] : 0ull;
        if (hi > T2 && hn <= T2) { bc.b2 = i; bc.above = hn; }
      }
    }
    __syncthreads();
    const int b2p = bc.b2;
    const unsigned long long Sfix = S1 + bc.above;
    t2_key = ((unsigned)b0p << 21) | ((unsigned)b1p << 10) | (unsigned)b2p;
    const int c_t = (int)C2[b2p];
    e_t = expf(keyf(t2_key) - m);
    // ties kept by top-p: 1 + floor((T - S)/e_t), clamped to [1, c_t]
    const double Td = (double)topp * ((double)Z1fix / FIXS);
    const double Sd = (double)Sfix / FIXS;
    const double jmd = (Td - Sd) / (double)e_t;
    int rem_p;
    if (jmd >= (double)c_t) rem_p = c_t;
    else {
      rem_p = (int)jmd + 1;
      if (rem_p > c_t) rem_p = c_t;
      if (rem_p < 1) rem_p = 1;
    }
    rem2 = rem_p;
    const unsigned long long Z2fix =
        Sfix + (unsigned long long)(unsigned)rem_p *
                   (unsigned long long)((double)e_t * FIXS);
    Z2d = (double)Z2fix / FIXS;
  } else {
    if (ka) { t2_key = tk_key; rem2 = rem_k; e_t = e_tk; }
    else    { all_mode = 1; }
    Z2d = (double)Z1fix / FIXS;
  }

  // ---------------- Pass 7: min-p + Z3 + tie list ----------------
  if (tid == 0) { tie_n = 0; bc.I2 = IMAXI; }
  __syncthreads();
  const float Z2f = (float)Z2d;
  const float thr = minp * (1.0f / Z2f);   // min_p * top_prob, fp32 shapes
  double zp = 0.0;
  FOR_ELEMS(
    unsigned key = fkey(x);
    if (all_mode || key > t2_key) {
      float e = expf(x - m);
      float q1 = e / Z2f;
      if (!(q1 < thr)) zp += (double)e;
    } else if (key == t2_key) {
      int p = atomicAdd(&tie_n, 1);
      if (p < TIE_CAP) C2[p] = (unsigned)idx;
    }
  )
  for (int o = 32; o > 0; o >>= 1) zp += __shfl_down(zp, o);
  if ((tid & 63) == 0) redd[tid >> 6] = zp;
  __syncthreads();
  int class_ok = 1;
  if (!all_mode) { float q1t = e_t / Z2f; class_ok = !(q1t < thr); }
  if (tid == 0) {
    double z3 = 0.0;
    for (int i = 0; i < 16; ++i) z3 += redd[i];
    if (!all_mode && class_ok) z3 += (double)rem2 * (double)e_t;
    bc.Z3 = z3;
  }
  __syncthreads();
  const int tn = tie_n;
  if (!all_mode && rem2 < tn && tn <= TIE_CAP) {
    if (tid < tn) {                       // select (rem2-1)-th smallest index
      unsigned mine = C2[tid];
      int r = 0;
      for (int j = 0; j < tn; ++j) r += (C2[j] < mine);
      if (r == rem2 - 1) bc.I2 = (int)mine;
    }
  }
  __syncthreads();
  const int I2 = bc.I2;
  const double Z3d = bc.Z3;

  // ---------------- Pass 8: Gumbel-max argmax over kept ----------------
  const float Z3f = (float)Z3d;
  const unsigned ibase = (unsigned)row * (unsigned)VOC;
  float bw = -INFINITY; int bi = IMAXI;
  FOR_ELEMS(
    unsigned key = fkey(x);
    bool kp = all_mode || key > t2_key || (key == t2_key && idx <= I2);
    if (kp) {
      float e = expf(x - m);
      float q1 = e / Z2f;
      if (!(q1 < thr)) {
        float w = logf(e / Z3f) + gumbel_at(ibase + (unsigned)idx);
        if (w > bw) { bw = w; bi = idx; }
        else if (w == bw && idx < bi) { bi = idx; }
      }
    }
  )
  for (int o = 32; o > 0; o >>= 1) {
    float ow = __shfl_down(bw, o);
    int   oi = __shfl_down(bi, o);
    if (ow > bw || (ow == bw && oi < bi)) { bw = ow; bi = oi; }
  }
  if ((tid & 63) == 0) { redw[tid >> 6] = bw; redi[tid >> 6] = bi; }
  __syncthreads();
  if (tid == 0) {
    float w = redw[0]; int ii = redi[0];
    for (int i = 1; i < 16; ++i)
      if (redw[i] > w || (redw[i] == w && redi[i] < ii)) { w = redw[i]; ii = redi[i]; }
    out[row] = ii;
  }
}

extern "C" void kernel_launch(void* const* d_in, const int* in_sizes, int n_in,
                              void* d_out, int out_size, void* d_ws, size_t ws_size,
                              hipStream_t stream) {
  (void)n_in; (void)d_ws; (void)ws_size; (void)out_size;
  const float* logits = (const float*)d_in[0];
  const float* temps  = (const float*)d_in[1];
  const float* topps  = (const float*)d_in[2];
  const int*   topks  = (const int*)d_in[3];
  const float* minps  = (const float*)d_in[4];
  int* out = (int*)d_out;
  const int rows = in_sizes[1];   // B = 128
  batch_sampler_kernel<<<dim3(rows), dim3(TPB), 0, stream>>>(
      logits, temps, topps, topks, minps, out);
}

// Round 2
// 193.709 us; speedup vs baseline: 1.6575x; 1.6575x over previous
//
#include <hip/hip_runtime.h>

// BatchSampler rnd2: top-k-first capture strategy.
// P12 (single full stream): raw max + x-key count hist (u32) + per-span max-key
//   table sgmax (prunes later passes).
// Top-k radix descent (11/11/10) on counts, selective via sgmax -> tk_key, rem_k.
// FAST path (k>0 and survivors<=2048): capture (key,idx) with key>=tk_key into
//   LDS, bitonic sort (~key<<32|idx == desc value, asc index = exact reference
//   rank order), double prefix scan -> top-p cut, min-p cut, gumbel argmax —
//   all in LDS on <=2048 entries.
// HEAVY path (k==0 row or tie overflow): round-1 verified pipeline (fixed-point
//   sum-hist descents + full min-p/gumbel passes), sgmax-pruned where legal.

#define TPB 1024
#define VOC 128256
#define V4 (VOC / 4)
#define NSPAN 8               // 8 spans x 4 chunks x TPB x 4 elems >= VOC
#define NBINS 2048
#define CAP 2048
#define TIE_CAP 1024
#define IMAXI 0x7fffffff
#define FIXS 1.7592186044416e13   // 2^44

__device__ __forceinline__ unsigned fkey(float x) {
  unsigned b = __float_as_uint(x);
  return b ^ ((b & 0x80000000u) ? 0xFFFFFFFFu : 0x80000000u);
}
__device__ __forceinline__ float keyf(unsigned k) {
  unsigned b = (k & 0x80000000u) ? (k ^ 0x80000000u) : ~k;
  return __uint_as_float(b);
}
__device__ __forceinline__ unsigned rotl32(unsigned v, int r) {
  return (v << r) | (v >> (32 - r));
}

// JAX threefry2x32, key=(0,42), partitionable path: counters (0,i), out o1^o2.
__device__ __forceinline__ float gumbel_at(unsigned i) {
  const unsigned ks1 = 42u;
  const unsigned ks2 = 0x1BD11BDAu ^ 42u;
  unsigned x0 = 0u;
  unsigned x1 = i + ks1;
  x0 += x1; x1 = rotl32(x1, 13); x1 ^= x0;
  x0 += x1; x1 = rotl32(x1, 15); x1 ^= x0;
  x0 += x1; x1 = rotl32(x1, 26); x1 ^= x0;
  x0 += x1; x1 = rotl32(x1, 6);  x1 ^= x0;
  x0 += ks1; x1 += ks2 + 1u;
  x0 += x1; x1 = rotl32(x1, 17); x1 ^= x0;
  x0 += x1; x1 = rotl32(x1, 29); x1 ^= x0;
  x0 += x1; x1 = rotl32(x1, 16); x1 ^= x0;
  x0 += x1; x1 = rotl32(x1, 24); x1 ^= x0;
  x0 += ks2; x1 += 0u + 2u;
  x0 += x1; x1 = rotl32(x1, 13); x1 ^= x0;
  x0 += x1; x1 = rotl32(x1, 15); x1 ^= x0;
  x0 += x1; x1 = rotl32(x1, 26); x1 ^= x0;
  x0 += x1; x1 = rotl32(x1, 6);  x1 ^= x0;
  x0 += 0u; x1 += ks1 + 3u;
  x0 += x1; x1 = rotl32(x1, 17); x1 ^= x0;
  x0 += x1; x1 = rotl32(x1, 29); x1 ^= x0;
  x0 += x1; x1 = rotl32(x1, 16); x1 ^= x0;
  x0 += x1; x1 = rotl32(x1, 24); x1 ^= x0;
  x0 += ks1; x1 += ks2 + 4u;
  x0 += x1; x1 = rotl32(x1, 13); x1 ^= x0;
  x0 += x1; x1 = rotl32(x1, 15); x1 ^= x0;
  x0 += x1; x1 = rotl32(x1, 26); x1 ^= x0;
  x0 += x1; x1 = rotl32(x1, 6);  x1 ^= x0;
  x0 += ks2; x1 += 0u + 5u;
  unsigned bits = x0 ^ x1;
  unsigned fb = (bits >> 9) | 0x3f800000u;
  float f = __uint_as_float(fb) - 1.0f;
  float u = (f > 0.0f) ? f : 1.17549435e-38f;
  return -logf(-logf(u));
}

// Inclusive suffix scan H[i] = sum_{j>=i} H[j]
__device__ __forceinline__ void scan64(unsigned long long* H, int n, int tid) {
  for (int d = 1; d < n; d <<= 1) {
    unsigned long long v0 = 0ull, v1 = 0ull;
    int i0 = tid, i1 = tid + TPB;
    bool a0 = (i0 < n), a1 = (i1 < n);
    if (a0) { v0 = H[i0]; if (i0 + d < n) v0 += H[i0 + d]; }
    if (a1) { v1 = H[i1]; if (i1 + d < n) v1 += H[i1 + d]; }
    __syncthreads();
    if (a0) H[i0] = v0;
    if (a1) H[i1] = v1;
    __syncthreads();
  }
}
__device__ __forceinline__ void scan32(unsigned* H, int n, int tid) {
  for (int d = 1; d < n; d <<= 1) {
    unsigned v0 = 0u, v1 = 0u;
    int i0 = tid, i1 = tid + TPB;
    bool a0 = (i0 < n), a1 = (i1 < n);
    if (a0) { v0 = H[i0]; if (i0 + d < n) v0 += H[i0 + d]; }
    if (a1) { v1 = H[i1]; if (i1 + d < n) v1 += H[i1 + d]; }
    __syncthreads();
    if (a0) H[i0] = v0;
    if (a1) H[i1] = v1;
    __syncthreads();
  }
}

// Pruned row stream: spans of 4 chunks; skip span if its max key < TH<<16.
#define FOR_SPANS(TH, ...)                                                    \
  for (int cs_ = 0; cs_ < NSPAN; ++cs_) {                                     \
    if ((unsigned)sgmax[cs_ * TPB + tid] >= (unsigned)(TH)) {                 \
      for (int cc_ = 0; cc_ < 4; ++cc_) {                                     \
        const int i4_ = (cs_ * 4 + cc_) * TPB + tid;                          \
        if (i4_ < V4) {                                                       \
          const float4 L_ = ((const float4*)rowp)[i4_];                       \
          const float xs_[4] = { L_.x / tclamp, L_.y / tclamp,                \
                                 L_.z / tclamp, L_.w / tclamp };              \
          const int base_ = i4_ * 4;                                          \
          for (int j_ = 0; j_ < 4; ++j_) {                                    \
            const int idx = base_ + j_; const float x = xs_[j_];              \
            __VA_ARGS__                                                       \
          }                                                                   \
        }                                                                     \
      }                                                                       \
    }                                                                         \
  }

extern "C" __global__ void __launch_bounds__(TPB)
batch_sampler_kernel(const float* __restrict__ logits,
                     const float* __restrict__ temps,
                     const float* __restrict__ topps,
                     const int*   __restrict__ topks,
                     const float* __restrict__ minps,
                     int* __restrict__ out)
{
  __shared__ unsigned short sgmax[NSPAN * TPB];   // 16 KB per-span max key >>16
  __shared__ unsigned Hc[NBINS];                  // 8 KB counts / tie list
  __shared__ unsigned long long A[CAP];           // 16 KB capture+sort / u64 hist
  __shared__ double D[TPB];                       // 8 KB prefix sums
  __shared__ float redw[16];
  __shared__ int   redi[16];
  __shared__ double redd[16];
  __shared__ float sh_m;
  __shared__ int sh_b0, sh_b1, sh_b2;
  __shared__ unsigned sh_above;
  __shared__ unsigned long long sh_ab64;
  __shared__ int sh_n, sh_p, sh_tn, sh_I2;
  __shared__ double sh_Z3;

  const int tid = threadIdx.x;
  const int row = blockIdx.x;
  const float* rowp = logits + (size_t)row * VOC;
  const float tclamp = fmaxf(temps[row], 1e-8f);
  const float topp = topps[row];
  const float minp = minps[row];
  const int k = topks[row];
  const bool ka = (k > 0) && (k < VOC);

  // ---------------- P12: raw max + L0 count hist + sgmax (ONE full pass) ----
  for (int i = tid; i < NBINS; i += TPB) Hc[i] = 0u;
  __syncthreads();
  float rmax = -INFINITY;
  for (int cs = 0; cs < NSPAN; ++cs) {
    unsigned gm = 0u;
    for (int cc = 0; cc < 4; ++cc) {
      const int i4 = (cs * 4 + cc) * TPB + tid;
      if (i4 < V4) {
        const float4 L = ((const float4*)rowp)[i4];
        rmax = fmaxf(rmax, fmaxf(fmaxf(L.x, L.y), fmaxf(L.z, L.w)));
        const float xs[4] = { L.x / tclamp, L.y / tclamp, L.z / tclamp, L.w / tclamp };
        for (int j = 0; j < 4; ++j) {
          unsigned key = fkey(xs[j]);
          gm = max(gm, key);
          atomicAdd(&Hc[key >> 21], 1u);
        }
      }
    }
    sgmax[cs * TPB + tid] = (unsigned short)(gm >> 16);
  }
  for (int o = 32; o > 0; o >>= 1) rmax = fmaxf(rmax, __shfl_down(rmax, o));
  if ((tid & 63) == 0) redw[tid >> 6] = rmax;
  __syncthreads();
  if (tid == 0) {
    float mm = redw[0];
    for (int i = 1; i < 16; ++i) mm = fmaxf(mm, redw[i]);
    sh_m = mm / tclamp;        // == max_i fl(L_i/t) since fl-div is monotone
  }
  __syncthreads();
  const float m = sh_m;

  // ---------------- Top-k radix descent on counts (sgmax-pruned) -----------
  unsigned tk_key = 0u; int rem_k = 0, c_t = 0;
  if (ka) {
    scan32(Hc, NBINS, tid);
    unsigned kku = (unsigned)k;
    for (int i = tid; i < NBINS; i += TPB) {
      unsigned hi = Hc[i], hn = (i + 1 < NBINS) ? Hc[i + 1] : 0u;
      if (hi >= kku && hn < kku) { sh_b0 = i; sh_above = hn; }
    }
    __syncthreads();
    const int b0 = sh_b0; kku -= sh_above;
    __syncthreads();
    for (int i = tid; i < NBINS; i += TPB) Hc[i] = 0u;
    __syncthreads();
    FOR_SPANS((unsigned short)(b0 << 5),
      (void)idx;
      unsigned key = fkey(x);
      if ((int)(key >> 21) == b0) atomicAdd(&Hc[(key >> 10) & 0x7FFu], 1u);
    )
    __syncthreads();
    scan32(Hc, NBINS, tid);
    for (int i = tid; i < NBINS; i += TPB) {
      unsigned hi = Hc[i], hn = (i + 1 < NBINS) ? Hc[i + 1] : 0u;
      if (hi >= kku && hn < kku) { sh_b1 = i; sh_above = hn; }
    }
    __syncthreads();
    const int b1 = sh_b1; kku -= sh_above;
    __syncthreads();
    for (int i = tid; i < NBINS; i += TPB) Hc[i] = 0u;
    __syncthreads();
    const unsigned pathk = ((unsigned)b0 << 11) | (unsigned)b1;
    FOR_SPANS((unsigned short)(pathk >> 6),
      (void)idx;
      unsigned key = fkey(x);
      if ((key >> 10) == pathk) atomicAdd(&Hc[key & 0x3FFu], 1u);
    )
    __syncthreads();
    scan32(Hc, 1024, tid);
    for (int i = tid; i < 1024; i += TPB) {
      unsigned hi = Hc[i], hn = (i + 1 < 1024) ? Hc[i + 1] : 0u;
      if (hi >= kku && hn < kku) { sh_b2 = i; sh_above = hn; }
    }
    __syncthreads();
    const int b2 = sh_b2;
    rem_k = (int)(kku - sh_above);
    tk_key = ((unsigned)b0 << 21) | ((unsigned)b1 << 10) | (unsigned)b2;
    c_t = (int)(Hc[b2] - ((b2 + 1 < 1024) ? Hc[b2 + 1] : 0u));
    __syncthreads();
  }
  const float e_tk = ka ? expf(keyf(tk_key) - m) : 0.0f;
  const int n_cap = ka ? (k - rem_k) + c_t : IMAXI;
  const bool fast = ka && (n_cap <= CAP);

  if (fast) {
    // ============ FAST PATH: capture survivors, all-in-LDS pipeline ========
    if (tid == 0) sh_n = 0;
    __syncthreads();
    const unsigned short tk16 = (unsigned short)(tk_key >> 16);
    FOR_SPANS(tk16,
      unsigned key = fkey(x);
      if (key >= tk_key) {
        int p = atomicAdd(&sh_n, 1);
        A[p] = ((unsigned long long)(~key) << 32) | (unsigned)idx;
      }
    )
    __syncthreads();
    const int n = sh_n;                 // == n_cap <= 2048
    int S = 2; while (S < n) S <<= 1;
    for (int i = n + tid; i < S; i += TPB) A[i] = ~0ull;
    // bitonic sort ascending (~key,idx) == key desc, idx asc (= ref rank order)
    for (int size = 2; size <= S; size <<= 1)
      for (int stride = size >> 1; stride > 0; stride >>= 1) {
        __syncthreads();
        for (int i = tid; i < S; i += TPB) {
          int j = i ^ stride;
          if (j > i) {
            unsigned long long a = A[i], b = A[j];
            bool up = ((i & size) == 0);
            if ((a > b) == up) { A[i] = b; A[j] = a; }
          }
        }
      }
    __syncthreads();
    // positions 0..k-1 are the top-k kept set in exact reference rank order
    unsigned key_i = 0u, idx_i = 0u; float e_i = 0.0f;
    const bool valid = (tid < k);
    if (valid) {
      unsigned long long a = A[tid];
      key_i = ~(unsigned)(a >> 32);
      idx_i = (unsigned)a;
      e_i = expf(keyf(key_i) - m);
    }
    D[tid] = valid ? (double)e_i : 0.0;
    __syncthreads();
    for (int d = 1; d < TPB; d <<= 1) {         // inclusive prefix scan
      double nv = D[tid];
      if (tid >= d) nv += D[tid - d];
      __syncthreads();
      D[tid] = nv;
      __syncthreads();
    }
    const double Z1 = D[k - 1];
    const double T = (double)topp * Z1;
    // top-p: keep position i iff i==0 or cum[i-1] <= T  (prefix property)
    if (tid == 0) sh_p = 0;
    __syncthreads();
    if (valid) {
      bool kept = (tid == 0) || (D[tid - 1] <= T);
      if (kept) atomicMax(&sh_p, tid);
    }
    __syncthreads();
    const int p2 = sh_p + 1;
    const float Z2f = (float)D[p2 - 1];
    // min-p: top_prob = e0/Z2 (e0 == expf(0) == 1), survivors are a prefix
    float e0;
    {
      unsigned long long a0 = A[0];
      e0 = expf(keyf(~(unsigned)(a0 >> 32)) - m);
    }
    const float thr = minp * (e0 / Z2f);
    __syncthreads();
    if (tid == 0) sh_p = 0;
    __syncthreads();
    if (valid && tid < p2) {
      float q = e_i / Z2f;
      if (!(q < thr)) atomicMax(&sh_p, tid);
    }
    __syncthreads();
    const int p3 = sh_p + 1;
    const float Z3f = (float)D[p3 - 1];
    // gumbel-max over final kept prefix
    float bw = -INFINITY; int bi = IMAXI;
    if (valid && tid < p3) {
      bw = logf(e_i / Z3f) + gumbel_at((unsigned)row * (unsigned)VOC + idx_i);
      bi = (int)idx_i;
    }
    for (int o = 32; o > 0; o >>= 1) {
      float ow = __shfl_down(bw, o);
      int   oi = __shfl_down(bi, o);
      if (ow > bw || (ow == bw && oi < bi)) { bw = ow; bi = oi; }
    }
    if ((tid & 63) == 0) { redw[tid >> 6] = bw; redi[tid >> 6] = bi; }
    __syncthreads();
    if (tid == 0) {
      float w = redw[0]; int ii = redi[0];
      for (int i = 1; i < 16; ++i)
        if (redw[i] > w || (redw[i] == w && redi[i] < ii)) { w = redw[i]; ii = redi[i]; }
      out[row] = ii;
    }
  } else {
    // ============ HEAVY PATH (k==0 row or tie overflow): round-1 logic =====
    const bool hk = ka;
    const unsigned long long e_tk_fix = (unsigned long long)((double)e_tk * FIXS);
    unsigned long long* H = A;
    __syncthreads();
    for (int i = tid; i < NBINS; i += TPB) H[i] = 0ull;
    __syncthreads();
    const unsigned short thA = hk ? (unsigned short)(tk_key >> 16) : (unsigned short)0;
    FOR_SPANS(thA,
      (void)idx;
      unsigned key = fkey(x);
      if (!hk || key > tk_key) {
        float e = expf(x - m);
        unsigned long long ef = (unsigned long long)((double)e * FIXS);
        if (ef) atomicAdd(&H[key >> 21], ef);
      }
    )
    __syncthreads();
    if (tid == 0 && hk) H[tk_key >> 21] += (unsigned long long)(unsigned)rem_k * e_tk_fix;
    __syncthreads();
    scan64(H, NBINS, tid);
    const unsigned long long Z1fix = H[0];
    const unsigned long long Tfix = (unsigned long long)((double)topp * (double)Z1fix);
    const int keepall = (Z1fix <= Tfix);

    unsigned t2_key = 0u; int rem2 = 0, all_mode = 0;
    double Z2d = 0.0; float e_t = 0.0f;

    if (!keepall) {
      for (int i = tid; i < NBINS; i += TPB) {
        unsigned long long hi = H[i], hn = (i + 1 < NBINS) ? H[i + 1] : 0ull;
        if (hi > Tfix && hn <= Tfix) { sh_b0 = i; sh_ab64 = hn; }
      }
      __syncthreads();
      const int b0p = sh_b0;
      const unsigned long long S0 = sh_ab64;
      __syncthreads();
      for (int i = tid; i < NBINS; i += TPB) H[i] = 0ull;
      __syncthreads();
      FOR_SPANS((unsigned short)(b0p << 5),
        (void)idx;
        unsigned key = fkey(x);
        if ((int)(key >> 21) == b0p && (!hk || key > tk_key)) {
          float e = expf(x - m);
          unsigned long long ef = (unsigned long long)((double)e * FIXS);
          if (ef) atomicAdd(&H[(key >> 10) & 0x7FFu], ef);
        }
      )
      __syncthreads();
      if (tid == 0 && hk && (int)(tk_key >> 21) == b0p)
        H[(tk_key >> 10) & 0x7FFu] += (unsigned long long)(unsigned)rem_k * e_tk_fix;
      __syncthreads();
      scan64(H, NBINS, tid);
      {
        const unsigned long long T1 = Tfix - S0;
        for (int i = tid; i < NBINS; i += TPB) {
          unsigned long long hi = H[i], hn = (i + 1 < NBINS) ? H[i + 1] : 0ull;
          if (hi > T1 && hn <= T1) { sh_b1 = i; sh_ab64 = hn; }
        }
      }
      __syncthreads();
      const int b1p = sh_b1;
      const unsigned long long S1 = S0 + sh_ab64;
      __syncthreads();
      for (int i = tid; i < NBINS; i += TPB) H[i] = 0ull;
      for (int i = tid; i < 1024; i += TPB) Hc[i] = 0u;
      __syncthreads();
      const unsigned pathp = ((unsigned)b0p << 11) | (unsigned)b1p;
      FOR_SPANS((unsigned short)(pathp >> 6),
        (void)idx;
        unsigned key = fkey(x);
        if ((key >> 10) == pathp && (!hk || key > tk_key)) {
          float e = expf(x - m);
          unsigned long long ef = (unsigned long long)((double)e * FIXS);
          atomicAdd(&H[key & 0x3FFu], ef);
          atomicAdd(&Hc[key & 0x3FFu], 1u);
        }
      )
      __syncthreads();
      if (tid == 0 && hk && (tk_key >> 10) == pathp) {
        H[tk_key & 0x3FFu] += (unsigned long long)(unsigned)rem_k * e_tk_fix;
        Hc[tk_key & 0x3FFu] += (unsigned)rem_k;
      }
      __syncthreads();
      scan64(H, 1024, tid);
      {
        const unsigned long long T2 = Tfix - S1;
        for (int i = tid; i < 1024; i += TPB) {
          unsigned long long hi = H[i], hn = (i + 1 < 1024) ? H[i + 1] : 0ull;
          if (hi > T2 && hn <= T2) { sh_b2 = i; sh_ab64 = hn; }
        }
      }
      __syncthreads();
      const int b2p = sh_b2;
      const unsigned long long Sfix = S1 + sh_ab64;
      t2_key = ((unsigned)b0p << 21) | ((unsigned)b1p << 10) | (unsigned)b2p;
      const int c_t2 = (int)Hc[b2p];
      e_t = expf(keyf(t2_key) - m);
      const double Td = (double)topp * ((double)Z1fix / FIXS);
      const double Sd = (double)Sfix / FIXS;
      const double jmd = (Td - Sd) / (double)e_t;
      int rem_p;
      if (jmd >= (double)c_t2) rem_p = c_t2;
      else {
        rem_p = (int)jmd + 1;
        if (rem_p > c_t2) rem_p = c_t2;
        if (rem_p < 1) rem_p = 1;
      }
      rem2 = rem_p;
      const unsigned long long Z2fix =
          Sfix + (unsigned long long)(unsigned)rem_p *
                     (unsigned long long)((double)e_t * FIXS);
      Z2d = (double)Z2fix / FIXS;
    } else {
      if (hk) { t2_key = tk_key; rem2 = rem_k; e_t = e_tk; }
      else    { all_mode = 1; }
      Z2d = (double)Z1fix / FIXS;
    }

    // min-p + Z3 + tie list
    if (tid == 0) { sh_tn = 0; sh_I2 = IMAXI; }
    __syncthreads();
    const unsigned short th7 = all_mode ? (unsigned short)0
                                        : (unsigned short)(t2_key >> 16);
    const float Z2f = (float)Z2d;
    const float thr = minp * (1.0f / Z2f);
    double zp = 0.0;
    FOR_SPANS(th7,
      unsigned key = fkey(x);
      if (all_mode || key > t2_key) {
        float e = expf(x - m);
        float q1 = e / Z2f;
        if (!(q1 < thr)) zp += (double)e;
      } else if (key == t2_key) {
        int p = atomicAdd(&sh_tn, 1);
        if (p < TIE_CAP) Hc[p] = (unsigned)idx;
      }
    )
    for (int o = 32; o > 0; o >>= 1) zp += __shfl_down(zp, o);
    if ((tid & 63) == 0) redd[tid >> 6] = zp;
    __syncthreads();
    int class_ok = 1;
    if (!all_mode) { float q1t = e_t / Z2f; class_ok = !(q1t < thr); }
    if (tid == 0) {
      double z3 = 0.0;
      for (int i = 0; i < 16; ++i) z3 += redd[i];
      if (!all_mode && class_ok) z3 += (double)rem2 * (double)e_t;
      sh_Z3 = z3;
    }
    __syncthreads();
    const int tn = sh_tn;
    if (!all_mode && rem2 < tn && tn <= TIE_CAP) {
      if (tid < tn) {
        unsigned mine = Hc[tid];
        int r = 0;
        for (int j = 0; j < tn; ++j) r += (Hc[j] < mine);
        if (r == rem2 - 1) sh_I2 = (int)mine;
      }
    }
    __syncthreads();
    const int I2 = sh_I2;
    const float Z3f = (float)sh_Z3;
    // gumbel argmax
    float bw = -INFINITY; int bi = IMAXI;
    FOR_SPANS(th7,
      unsigned key = fkey(x);
      bool kp = all_mode || key > t2_key || (key == t2_key && idx <= I2);
      if (kp) {
        float e = expf(x - m);
        float q1 = e / Z2f;
        if (!(q1 < thr)) {
          float w = logf(e / Z3f) + gumbel_at((unsigned)row * (unsigned)VOC + (unsigned)idx);
          if (w > bw) { bw = w; bi = idx; }
          else if (w == bw && idx < bi) bi = idx;
        }
      }
    )
    for (int o = 32; o > 0; o >>= 1) {
      float ow = __shfl_down(bw, o);
      int   oi = __shfl_down(bi, o);
      if (ow > bw || (ow == bw && oi < bi)) { bw = ow; bi = oi; }
    }
    if ((tid & 63) == 0) { redw[tid >> 6] = bw; redi[tid >> 6] = bi; }
    __syncthreads();
    if (tid == 0) {
      float w = redw[0]; int ii = redi[0];
      for (int i = 1; i < 16; ++i)
        if (redw[i] > w || (redw[i] == w && redi[i] < ii)) { w = redw[i]; ii = redi[i]; }
      out[row] = ii;
    }
  }
}

extern "C" void kernel_launch(void* const* d_in, const int* in_sizes, int n_in,
                              void* d_out, int out_size, void* d_ws, size_t ws_size,
                              hipStream_t stream) {
  (void)n_in; (void)d_ws; (void)ws_size; (void)out_size;
  const float* logits = (const float*)d_in[0];
  const float* temps  = (const float*)d_in[1];
  const float* topps  = (const float*)d_in[2];
  const int*   topks  = (const int*)d_in[3];
  const float* minps  = (const float*)d_in[4];
  int* out = (int*)d_out;
  const int rows = in_sizes[1];   // B = 128
  batch_sampler_kernel<<<dim3(rows), dim3(TPB), 0, stream>>>(
      logits, temps, topps, topks, minps, out);
}

// Round 3
// 190.210 us; speedup vs baseline: 1.6880x; 1.0184x over previous
//
#include <hip/hip_runtime.h>

// BatchSampler rnd3: chip-wide split streaming pass + per-row LDS pipeline.
// Kernel A: 8 blocks/row x 512 thr — per-slot max-key table (sgmax), partial
//   L0 count hist (u16), per-block max key. Full-chip streaming.
// Kernel B: 1 block/row x 1024 thr — merge hist/sgmax/kmax, then round-2
//   verified pipeline: top-k radix descent (pruned), fast capture+bitonic
//   path (<=2048 survivors), heavy fixed-point fallback.

#define TPB 1024
#define TPA 512
#define SPLIT 8
#define VOC 128256
#define V4 (VOC / 4)
#define NSPAN 8
#define NSLOT (NSPAN * TPB)   // 8192 slots/row
#define NBINS 2048
#define CAP 2048
#define TIE_CAP 1024
#define IMAXI 0x7fffffff
#define FIXS 1.7592186044416e13   // 2^44

// ws layout (bytes)
#define WS_HIST 0                         // u16 [128][SPLIT][NBINS]  = 4 MB
#define WS_SG   (128 * SPLIT * NBINS * 2) // u16 [128][NSLOT]         = 2 MB
#define WS_KMAX (WS_SG + 128 * NSLOT * 2) // u32 [128][SPLIT]         = 4 KB

__device__ __forceinline__ unsigned fkey(float x) {
  unsigned b = __float_as_uint(x);
  return b ^ ((b & 0x80000000u) ? 0xFFFFFFFFu : 0x80000000u);
}
__device__ __forceinline__ float keyf(unsigned k) {
  unsigned b = (k & 0x80000000u) ? (k ^ 0x80000000u) : ~k;
  return __uint_as_float(b);
}
__device__ __forceinline__ unsigned rotl32(unsigned v, int r) {
  return (v << r) | (v >> (32 - r));
}

// JAX threefry2x32, key=(0,42), partitionable path: counters (0,i), out o1^o2.
__device__ __forceinline__ float gumbel_at(unsigned i) {
  const unsigned ks1 = 42u;
  const unsigned ks2 = 0x1BD11BDAu ^ 42u;
  unsigned x0 = 0u;
  unsigned x1 = i + ks1;
  x0 += x1; x1 = rotl32(x1, 13); x1 ^= x0;
  x0 += x1; x1 = rotl32(x1, 15); x1 ^= x0;
  x0 += x1; x1 = rotl32(x1, 26); x1 ^= x0;
  x0 += x1; x1 = rotl32(x1, 6);  x1 ^= x0;
  x0 += ks1; x1 += ks2 + 1u;
  x0 += x1; x1 = rotl32(x1, 17); x1 ^= x0;
  x0 += x1; x1 = rotl32(x1, 29); x1 ^= x0;
  x0 += x1; x1 = rotl32(x1, 16); x1 ^= x0;
  x0 += x1; x1 = rotl32(x1, 24); x1 ^= x0;
  x0 += ks2; x1 += 0u + 2u;
  x0 += x1; x1 = rotl32(x1, 13); x1 ^= x0;
  x0 += x1; x1 = rotl32(x1, 15); x1 ^= x0;
  x0 += x1; x1 = rotl32(x1, 26); x1 ^= x0;
  x0 += x1; x1 = rotl32(x1, 6);  x1 ^= x0;
  x0 += 0u; x1 += ks1 + 3u;
  x0 += x1; x1 = rotl32(x1, 17); x1 ^= x0;
  x0 += x1; x1 = rotl32(x1, 29); x1 ^= x0;
  x0 += x1; x1 = rotl32(x1, 16); x1 ^= x0;
  x0 += x1; x1 = rotl32(x1, 24); x1 ^= x0;
  x0 += ks1; x1 += ks2 + 4u;
  x0 += x1; x1 = rotl32(x1, 13); x1 ^= x0;
  x0 += x1; x1 = rotl32(x1, 15); x1 ^= x0;
  x0 += x1; x1 = rotl32(x1, 26); x1 ^= x0;
  x0 += x1; x1 = rotl32(x1, 6);  x1 ^= x0;
  x0 += ks2; x1 += 0u + 5u;
  unsigned bits = x0 ^ x1;
  unsigned fb = (bits >> 9) | 0x3f800000u;
  float f = __uint_as_float(fb) - 1.0f;
  float u = (f > 0.0f) ? f : 1.17549435e-38f;
  return -logf(-logf(u));
}

__device__ __forceinline__ void scan64(unsigned long long* H, int n, int tid) {
  for (int d = 1; d < n; d <<= 1) {
    unsigned long long v0 = 0ull, v1 = 0ull;
    int i0 = tid, i1 = tid + TPB;
    bool a0 = (i0 < n), a1 = (i1 < n);
    if (a0) { v0 = H[i0]; if (i0 + d < n) v0 += H[i0 + d]; }
    if (a1) { v1 = H[i1]; if (i1 + d < n) v1 += H[i1 + d]; }
    __syncthreads();
    if (a0) H[i0] = v0;
    if (a1) H[i1] = v1;
    __syncthreads();
  }
}
__device__ __forceinline__ void scan32(unsigned* H, int n, int tid) {
  for (int d = 1; d < n; d <<= 1) {
    unsigned v0 = 0u, v1 = 0u;
    int i0 = tid, i1 = tid + TPB;
    bool a0 = (i0 < n), a1 = (i1 < n);
    if (a0) { v0 = H[i0]; if (i0 + d < n) v0 += H[i0 + d]; }
    if (a1) { v1 = H[i1]; if (i1 + d < n) v1 += H[i1 + d]; }
    __syncthreads();
    if (a0) H[i0] = v0;
    if (a1) H[i1] = v1;
    __syncthreads();
  }
}

#define FOR_SPANS(TH, ...)                                                    \
  for (int cs_ = 0; cs_ < NSPAN; ++cs_) {                                     \
    if ((unsigned)sgmax[cs_ * TPB + tid] >= (unsigned)(TH)) {                 \
      for (int cc_ = 0; cc_ < 4; ++cc_) {                                     \
        const int i4_ = (cs_ * 4 + cc_) * TPB + tid;                          \
        if (i4_ < V4) {                                                       \
          const float4 L_ = ((const float4*)rowp)[i4_];                       \
          const float xs_[4] = { L_.x / tclamp, L_.y / tclamp,                \
                                 L_.z / tclamp, L_.w / tclamp };              \
          const int base_ = i4_ * 4;                                          \
          for (int j_ = 0; j_ < 4; ++j_) {                                    \
            const int idx = base_ + j_; const float x = xs_[j_];              \
            __VA_ARGS__                                                       \
          }                                                                   \
        }                                                                     \
      }                                                                       \
    }                                                                         \
  }

// ================= Kernel A: chip-wide streaming stats =================
extern "C" __global__ void __launch_bounds__(TPA)
sampler_stats_kernel(const float* __restrict__ logits,
                     const float* __restrict__ temps,
                     unsigned char* __restrict__ ws)
{
  __shared__ unsigned Hl[NBINS];
  __shared__ unsigned redk[8];
  const int blk = blockIdx.x;
  const int row = blk / SPLIT;
  const int sb  = blk % SPLIT;
  const int tid = threadIdx.x;
  const float* rowp = logits + (size_t)row * VOC;
  const float tclamp = fmaxf(temps[row], 1e-8f);
  unsigned short* sg_out = (unsigned short*)(ws + WS_SG) + (size_t)row * NSLOT;
  unsigned short* h_out  = (unsigned short*)(ws + WS_HIST) +
                           ((size_t)row * SPLIT + sb) * NBINS;
  unsigned* kmax_out = (unsigned*)(ws + WS_KMAX);

  for (int i = tid; i < NBINS; i += TPA) Hl[i] = 0u;
  __syncthreads();

  unsigned bmax = 0u;
  for (int r = 0; r < 2; ++r) {
    const int slot = sb * 1024 + r * TPA + tid;   // slot in [0, NSLOT)
    const int cs = slot >> 10, tl = slot & 1023;
    unsigned gm = 0u;
    for (int cc = 0; cc < 4; ++cc) {
      const int i4 = (cs * 4 + cc) * TPB + tl;
      if (i4 < V4) {
        const float4 L = ((const float4*)rowp)[i4];
        const float xs[4] = { L.x / tclamp, L.y / tclamp,
                              L.z / tclamp, L.w / tclamp };
        for (int j = 0; j < 4; ++j) {
          unsigned key = fkey(xs[j]);
          gm = max(gm, key);
          atomicAdd(&Hl[key >> 21], 1u);
        }
      }
    }
    sg_out[slot] = (unsigned short)(gm >> 16);
    bmax = max(bmax, gm);
  }
  for (int o = 32; o > 0; o >>= 1) bmax = max(bmax, (unsigned)__shfl_down(bmax, o));
  if ((tid & 63) == 0) redk[tid >> 6] = bmax;
  __syncthreads();
  if (tid == 0) {
    unsigned mm = redk[0];
    for (int i = 1; i < TPA / 64; ++i) mm = max(mm, redk[i]);
    kmax_out[row * SPLIT + sb] = mm;
  }
  for (int i = tid; i < NBINS; i += TPA) h_out[i] = (unsigned short)Hl[i];
}

// ================= Kernel B: per-row selection pipeline =================
extern "C" __global__ void __launch_bounds__(TPB)
batch_sampler_kernel(const float* __restrict__ logits,
                     const float* __restrict__ temps,
                     const float* __restrict__ topps,
                     const int*   __restrict__ topks,
                     const float* __restrict__ minps,
                     const unsigned char* __restrict__ ws,
                     int* __restrict__ out)
{
  __shared__ unsigned short sgmax[NSLOT];         // 16 KB
  __shared__ unsigned Hc[NBINS];                  // 8 KB
  __shared__ unsigned long long A[CAP];           // 16 KB
  __shared__ double D[TPB];                       // 8 KB
  __shared__ float redw[16];
  __shared__ int   redi[16];
  __shared__ double redd[16];
  __shared__ float sh_m;
  __shared__ int sh_b0, sh_b1, sh_b2;
  __shared__ unsigned sh_above;
  __shared__ unsigned long long sh_ab64;
  __shared__ int sh_n, sh_p, sh_tn, sh_I2;
  __shared__ double sh_Z3;

  const int tid = threadIdx.x;
  const int row = blockIdx.x;
  const float* rowp = logits + (size_t)row * VOC;
  const float tclamp = fmaxf(temps[row], 1e-8f);
  const float topp = topps[row];
  const float minp = minps[row];
  const int k = topks[row];
  const bool ka = (k > 0) && (k < VOC);

  // ------- merge stats from kernel A -------
  {
    const unsigned* gsg = (const unsigned*)((const unsigned short*)(ws + WS_SG) +
                                            (size_t)row * NSLOT);
    for (int i = tid; i < NSLOT / 2; i += TPB) ((unsigned*)sgmax)[i] = gsg[i];
    const unsigned short* hp = (const unsigned short*)(ws + WS_HIST) +
                               (size_t)row * SPLIT * NBINS;
    for (int i = tid; i < NBINS; i += TPB) {
      unsigned s = 0;
      for (int b = 0; b < SPLIT; ++b) s += hp[b * NBINS + i];
      Hc[i] = s;
    }
    if (tid == 0) {
      const unsigned* kmax_in = (const unsigned*)(ws + WS_KMAX) + row * SPLIT;
      unsigned mm = kmax_in[0];
      for (int b = 1; b < SPLIT; ++b) mm = max(mm, kmax_in[b]);
      sh_m = keyf(mm);     // == max_i fl(L_i/t) (fl-div monotone, key bijective)
    }
  }
  __syncthreads();
  const float m = sh_m;

  // ---------------- Top-k radix descent on counts (sgmax-pruned) -----------
  unsigned tk_key = 0u; int rem_k = 0, c_t = 0;
  if (ka) {
    scan32(Hc, NBINS, tid);
    unsigned kku = (unsigned)k;
    for (int i = tid; i < NBINS; i += TPB) {
      unsigned hi = Hc[i], hn = (i + 1 < NBINS) ? Hc[i + 1] : 0u;
      if (hi >= kku && hn < kku) { sh_b0 = i; sh_above = hn; }
    }
    __syncthreads();
    const int b0 = sh_b0; kku -= sh_above;
    __syncthreads();
    for (int i = tid; i < NBINS; i += TPB) Hc[i] = 0u;
    __syncthreads();
    FOR_SPANS((unsigned short)(b0 << 5),
      (void)idx;
      unsigned key = fkey(x);
      if ((int)(key >> 21) == b0) atomicAdd(&Hc[(key >> 10) & 0x7FFu], 1u);
    )
    __syncthreads();
    scan32(Hc, NBINS, tid);
    for (int i = tid; i < NBINS; i += TPB) {
      unsigned hi = Hc[i], hn = (i + 1 < NBINS) ? Hc[i + 1] : 0u;
      if (hi >= kku && hn < kku) { sh_b1 = i; sh_above = hn; }
    }
    __syncthreads();
    const int b1 = sh_b1; kku -= sh_above;
    __syncthreads();
    for (int i = tid; i < NBINS; i += TPB) Hc[i] = 0u;
    __syncthreads();
    const unsigned pathk = ((unsigned)b0 << 11) | (unsigned)b1;
    FOR_SPANS((unsigned short)(pathk >> 6),
      (void)idx;
      unsigned key = fkey(x);
      if ((key >> 10) == pathk) atomicAdd(&Hc[key & 0x3FFu], 1u);
    )
    __syncthreads();
    scan32(Hc, 1024, tid);
    for (int i = tid; i < 1024; i += TPB) {
      unsigned hi = Hc[i], hn = (i + 1 < 1024) ? Hc[i + 1] : 0u;
      if (hi >= kku && hn < kku) { sh_b2 = i; sh_above = hn; }
    }
    __syncthreads();
    const int b2 = sh_b2;
    rem_k = (int)(kku - sh_above);
    tk_key = ((unsigned)b0 << 21) | ((unsigned)b1 << 10) | (unsigned)b2;
    c_t = (int)(Hc[b2] - ((b2 + 1 < 1024) ? Hc[b2 + 1] : 0u));
    __syncthreads();
  }
  const float e_tk = ka ? expf(keyf(tk_key) - m) : 0.0f;
  const int n_cap = ka ? (k - rem_k) + c_t : IMAXI;
  const bool fast = ka && (n_cap <= CAP);

  if (fast) {
    // ============ FAST PATH ============
    if (tid == 0) sh_n = 0;
    __syncthreads();
    const unsigned short tk16 = (unsigned short)(tk_key >> 16);
    FOR_SPANS(tk16,
      unsigned key = fkey(x);
      if (key >= tk_key) {
        int p = atomicAdd(&sh_n, 1);
        A[p] = ((unsigned long long)(~key) << 32) | (unsigned)idx;
      }
    )
    __syncthreads();
    const int n = sh_n;
    int S = 2; while (S < n) S <<= 1;
    for (int i = n + tid; i < S; i += TPB) A[i] = ~0ull;
    for (int size = 2; size <= S; size <<= 1)
      for (int stride = size >> 1; stride > 0; stride >>= 1) {
        __syncthreads();
        for (int i = tid; i < S; i += TPB) {
          int j = i ^ stride;
          if (j > i) {
            unsigned long long a = A[i], b = A[j];
            bool up = ((i & size) == 0);
            if ((a > b) == up) { A[i] = b; A[j] = a; }
          }
        }
      }
    __syncthreads();
    unsigned key_i = 0u, idx_i = 0u; float e_i = 0.0f;
    const bool valid = (tid < k);
    if (valid) {
      unsigned long long a = A[tid];
      key_i = ~(unsigned)(a >> 32);
      idx_i = (unsigned)a;
      e_i = expf(keyf(key_i) - m);
    }
    D[tid] = valid ? (double)e_i : 0.0;
    __syncthreads();
    for (int d = 1; d < TPB; d <<= 1) {
      double nv = D[tid];
      if (tid >= d) nv += D[tid - d];
      __syncthreads();
      D[tid] = nv;
      __syncthreads();
    }
    const double Z1 = D[k - 1];
    const double T = (double)topp * Z1;
    if (tid == 0) sh_p = 0;
    __syncthreads();
    if (valid) {
      bool kept = (tid == 0) || (D[tid - 1] <= T);
      if (kept) atomicMax(&sh_p, tid);
    }
    __syncthreads();
    const int p2 = sh_p + 1;
    const float Z2f = (float)D[p2 - 1];
    float e0;
    {
      unsigned long long a0 = A[0];
      e0 = expf(keyf(~(unsigned)(a0 >> 32)) - m);
    }
    const float thr = minp * (e0 / Z2f);
    __syncthreads();
    if (tid == 0) sh_p = 0;
    __syncthreads();
    if (valid && tid < p2) {
      float q = e_i / Z2f;
      if (!(q < thr)) atomicMax(&sh_p, tid);
    }
    __syncthreads();
    const int p3 = sh_p + 1;
    const float Z3f = (float)D[p3 - 1];
    float bw = -INFINITY; int bi = IMAXI;
    if (valid && tid < p3) {
      bw = logf(e_i / Z3f) + gumbel_at((unsigned)row * (unsigned)VOC + idx_i);
      bi = (int)idx_i;
    }
    for (int o = 32; o > 0; o >>= 1) {
      float ow = __shfl_down(bw, o);
      int   oi = __shfl_down(bi, o);
      if (ow > bw || (ow == bw && oi < bi)) { bw = ow; bi = oi; }
    }
    if ((tid & 63) == 0) { redw[tid >> 6] = bw; redi[tid >> 6] = bi; }
    __syncthreads();
    if (tid == 0) {
      float w = redw[0]; int ii = redi[0];
      for (int i = 1; i < 16; ++i)
        if (redw[i] > w || (redw[i] == w && redi[i] < ii)) { w = redw[i]; ii = redi[i]; }
      out[row] = ii;
    }
  } else {
    // ============ HEAVY PATH ============
    const bool hk = ka;
    const unsigned long long e_tk_fix = (unsigned long long)((double)e_tk * FIXS);
    unsigned long long* H = A;
    __syncthreads();
    for (int i = tid; i < NBINS; i += TPB) H[i] = 0ull;
    __syncthreads();
    const unsigned short thA = hk ? (unsigned short)(tk_key >> 16) : (unsigned short)0;
    FOR_SPANS(thA,
      (void)idx;
      unsigned key = fkey(x);
      if (!hk || key > tk_key) {
        float e = expf(x - m);
        unsigned long long ef = (unsigned long long)((double)e * FIXS);
        if (ef) atomicAdd(&H[key >> 21], ef);
      }
    )
    __syncthreads();
    if (tid == 0 && hk) H[tk_key >> 21] += (unsigned long long)(unsigned)rem_k * e_tk_fix;
    __syncthreads();
    scan64(H, NBINS, tid);
    const unsigned long long Z1fix = H[0];
    const unsigned long long Tfix = (unsigned long long)((double)topp * (double)Z1fix);
    const int keepall = (Z1fix <= Tfix);

    unsigned t2_key = 0u; int rem2 = 0, all_mode = 0;
    double Z2d = 0.0; float e_t = 0.0f;

    if (!keepall) {
      for (int i = tid; i < NBINS; i += TPB) {
        unsigned long long hi = H[i], hn = (i + 1 < NBINS) ? H[i + 1] : 0ull;
        if (hi > Tfix && hn <= Tfix) { sh_b0 = i; sh_ab64 = hn; }
      }
      __syncthreads();
      const int b0p = sh_b0;
      const unsigned long long S0 = sh_ab64;
      __syncthreads();
      for (int i = tid; i < NBINS; i += TPB) H[i] = 0ull;
      __syncthreads();
      FOR_SPANS((unsigned short)(b0p << 5),
        (void)idx;
        unsigned key = fkey(x);
        if ((int)(key >> 21) == b0p && (!hk || key > tk_key)) {
          float e = expf(x - m);
          unsigned long long ef = (unsigned long long)((double)e * FIXS);
          if (ef) atomicAdd(&H[(key >> 10) & 0x7FFu], ef);
        }
      )
      __syncthreads();
      if (tid == 0 && hk && (int)(tk_key >> 21) == b0p)
        H[(tk_key >> 10) & 0x7FFu] += (unsigned long long)(unsigned)rem_k * e_tk_fix;
      __syncthreads();
      scan64(H, NBINS, tid);
      {
        const unsigned long long T1 = Tfix - S0;
        for (int i = tid; i < NBINS; i += TPB) {
          unsigned long long hi = H[i], hn = (i + 1 < NBINS) ? H[i + 1] : 0ull;
          if (hi > T1 && hn <= T1) { sh_b1 = i; sh_ab64 = hn; }
        }
      }
      __syncthreads();
      const int b1p = sh_b1;
      const unsigned long long S1 = S0 + sh_ab64;
      __syncthreads();
      for (int i = tid; i < NBINS; i += TPB) H[i] = 0ull;
      for (int i = tid; i < 1024; i += TPB) Hc[i] = 0u;
      __syncthreads();
      const unsigned pathp = ((unsigned)b0p << 11) | (unsigned)b1p;
      FOR_SPANS((unsigned short)(pathp >> 6),
        (void)idx;
        unsigned key = fkey(x);
        if ((key >> 10) == pathp && (!hk || key > tk_key)) {
          float e = expf(x - m);
          unsigned long long ef = (unsigned long long)((double)e * FIXS);
          atomicAdd(&H[key & 0x3FFu], ef);
          atomicAdd(&Hc[key & 0x3FFu], 1u);
        }
      )
      __syncthreads();
      if (tid == 0 && hk && (tk_key >> 10) == pathp) {
        H[tk_key & 0x3FFu] += (unsigned long long)(unsigned)rem_k * e_tk_fix;
        Hc[tk_key & 0x3FFu] += (unsigned)rem_k;
      }
      __syncthreads();
      scan64(H, 1024, tid);
      {
        const unsigned long long T2 = Tfix - S1;
        for (int i = tid; i < 1024; i += TPB) {
          unsigned long long hi = H[i], hn = (i + 1 < 1024) ? H[i + 1] : 0ull;
          if (hi > T2 && hn <= T2) { sh_b2 = i; sh_ab64 = hn; }
        }
      }
      __syncthreads();
      const int b2p = sh_b2;
      const unsigned long long Sfix = S1 + sh_ab64;
      t2_key = ((unsigned)b0p << 21) | ((unsigned)b1p << 10) | (unsigned)b2p;
      const int c_t2 = (int)Hc[b2p];
      e_t = expf(keyf(t2_key) - m);
      const double Td = (double)topp * ((double)Z1fix / FIXS);
      const double Sd = (double)Sfix / FIXS;
      const double jmd = (Td - Sd) / (double)e_t;
      int rem_p;
      if (jmd >= (double)c_t2) rem_p = c_t2;
      else {
        rem_p = (int)jmd + 1;
        if (rem_p > c_t2) rem_p = c_t2;
        if (rem_p < 1) rem_p = 1;
      }
      rem2 = rem_p;
      const unsigned long long Z2fix =
          Sfix + (unsigned long long)(unsigned)rem_p *
                     (unsigned long long)((double)e_t * FIXS);
      Z2d = (double)Z2fix / FIXS;
    } else {
      if (hk) { t2_key = tk_key; rem2 = rem_k; e_t = e_tk; }
      else    { all_mode = 1; }
      Z2d = (double)Z1fix / FIXS;
    }

    if (tid == 0) { sh_tn = 0; sh_I2 = IMAXI; }
    __syncthreads();
    const unsigned short th7 = all_mode ? (unsigned short)0
                                        : (unsigned short)(t2_key >> 16);
    const float Z2f = (float)Z2d;
    const float thr = minp * (1.0f / Z2f);
    double zp = 0.0;
    FOR_SPANS(th7,
      unsigned key = fkey(x);
      if (all_mode || key > t2_key) {
        float e = expf(x - m);
        float q1 = e / Z2f;
        if (!(q1 < thr)) zp += (double)e;
      } else if (key == t2_key) {
        int p = atomicAdd(&sh_tn, 1);
        if (p < TIE_CAP) Hc[p] = (unsigned)idx;
      }
    )
    for (int o = 32; o > 0; o >>= 1) zp += __shfl_down(zp, o);
    if ((tid & 63) == 0) redd[tid >> 6] = zp;
    __syncthreads();
    int class_ok = 1;
    if (!all_mode) { float q1t = e_t / Z2f; class_ok = !(q1t < thr); }
    if (tid == 0) {
      double z3 = 0.0;
      for (int i = 0; i < 16; ++i) z3 += redd[i];
      if (!all_mode && class_ok) z3 += (double)rem2 * (double)e_t;
      sh_Z3 = z3;
    }
    __syncthreads();
    const int tn = sh_tn;
    if (!all_mode && rem2 < tn && tn <= TIE_CAP) {
      if (tid < tn) {
        unsigned mine = Hc[tid];
        int r = 0;
        for (int j = 0; j < tn; ++j) r += (Hc[j] < mine);
        if (r == rem2 - 1) sh_I2 = (int)mine;
      }
    }
    __syncthreads();
    const int I2 = sh_I2;
    const float Z3f = (float)sh_Z3;
    float bw = -INFINITY; int bi = IMAXI;
    FOR_SPANS(th7,
      unsigned key = fkey(x);
      bool kp = all_mode || key > t2_key || (key == t2_key && idx <= I2);
      if (kp) {
        float e = expf(x - m);
        float q1 = e / Z2f;
        if (!(q1 < thr)) {
          float w = logf(e / Z3f) + gumbel_at((unsigned)row * (unsigned)VOC + (unsigned)idx);
          if (w > bw) { bw = w; bi = idx; }
          else if (w == bw && idx < bi) bi = idx;
        }
      }
    )
    for (int o = 32; o > 0; o >>= 1) {
      float ow = __shfl_down(bw, o);
      int   oi = __shfl_down(bi, o);
      if (ow > bw || (ow == bw && oi < bi)) { bw = ow; bi = oi; }
    }
    if ((tid & 63) == 0) { redw[tid >> 6] = bw; redi[tid >> 6] = bi; }
    __syncthreads();
    if (tid == 0) {
      float w = redw[0]; int ii = redi[0];
      for (int i = 1; i < 16; ++i)
        if (redw[i] > w || (redw[i] == w && redi[i] < ii)) { w = redw[i]; ii = redi[i]; }
      out[row] = ii;
    }
  }
}

extern "C" void kernel_launch(void* const* d_in, const int* in_sizes, int n_in,
                              void* d_out, int out_size, void* d_ws, size_t ws_size,
                              hipStream_t stream) {
  (void)n_in; (void)ws_size; (void)out_size;
  const float* logits = (const float*)d_in[0];
  const float* temps  = (const float*)d_in[1];
  const float* topps  = (const float*)d_in[2];
  const int*   topks  = (const int*)d_in[3];
  const float* minps  = (const float*)d_in[4];
  int* out = (int*)d_out;
  const int rows = in_sizes[1];   // B = 128
  unsigned char* ws = (unsigned char*)d_ws;
  sampler_stats_kernel<<<dim3(rows * SPLIT), dim3(TPA), 0, stream>>>(
      logits, temps, ws);
  batch_sampler_kernel<<<dim3(rows), dim3(TPB), 0, stream>>>(
      logits, temps, topps, topks, minps, ws, out);
}